// Round 2
// baseline (382.281 us; speedup 1.0000x reference)
//
#include <hip/hip_runtime.h>
#include <hip/hip_bf16.h>

// HMM count-accumulation: trans_count[(label, pre)] += 1, emit_count[word, label] += 1
// over valid (non-pad) tokens. Output = [trans_count (65*65=4225) | emit_count (500000*64)].

constexpr int N_WORDS  = 500000;
constexpr int N_LABELS = 64;
constexpr int SEQ_LEN  = 512;
constexpr int BINS     = (N_LABELS + 1) * (N_LABELS + 1);  // 4225
constexpr int N_PART   = 64;                                // trans partials in ws
constexpr int BLOCK    = 1024;                              // 16 waves/block
constexpr int GRID     = 512;                               // 2 blocks/CU -> 32 waves/CU
constexpr int ZBLOCK   = 256;
constexpr int ZGRID    = 2048;

// Zero d_out (float) and the partials region of d_ws in one launch, 16B stores.
__global__ __launch_bounds__(ZBLOCK)
void zero_kernel(uint4* __restrict__ out, int out_quads, int out_size,
                 uint4* __restrict__ part, int part_quads) {
    const uint4 z = {0u, 0u, 0u, 0u};
    const int stride = gridDim.x * blockDim.x;
    const int total = out_quads + part_quads;
    for (int q = blockIdx.x * blockDim.x + threadIdx.x; q < total; q += stride) {
        if (q < out_quads) out[q] = z;
        else               part[q - out_quads] = z;
    }
    // scalar tail of out (out_size not divisible by 4)
    if (blockIdx.x == 0 && threadIdx.x < (out_size & 3)) {
        ((unsigned*)out)[(out_quads << 2) + threadIdx.x] = 0u;
    }
}

__global__ __launch_bounds__(BLOCK)
void count_kernel(const int* __restrict__ words,
                  const int* __restrict__ labels,
                  float* __restrict__ out,          // [BINS trans | N_WORDS*N_LABELS emit]
                  unsigned* __restrict__ part,      // [N_PART][BINS] uint partials (ws)
                  int nquads, int use_part) {
    __shared__ unsigned hist[BINS];
    for (int k = threadIdx.x; k < BINS; k += BLOCK) hist[k] = 0u;
    __syncthreads();

    float* __restrict__ emit = out + BINS;
    const int stride = gridDim.x * blockDim.x;
    for (int q = blockIdx.x * blockDim.x + threadIdx.x; q < nquads; q += stride) {
        const int i = q << 2;                      // base token index of this quad
        const int4 w4 = reinterpret_cast<const int4*>(words)[q];
        const int4 l4 = reinterpret_cast<const int4*>(labels)[q];
        const int j0 = i & (SEQ_LEN - 1);          // position within sequence
        // pre-label for first element of quad: sentinel 64 at j==0, else labels[i-1]
        int pre = (j0 == 0) ? N_LABELS : labels[i - 1];

        int wv[4] = {w4.x, w4.y, w4.z, w4.w};
        int lv[4] = {l4.x, l4.y, l4.z, l4.w};
        #pragma unroll
        for (int k = 0; k < 4; ++k) {
            const int w   = wv[k];
            const int lab = lv[k];
            if (w != 0) {                          // valid (non-pad) token
                atomicAdd(&hist[lab * (N_LABELS + 1) + pre], 1u);
                const int we = (w >= N_WORDS) ? 1 : w;   // UNK clamp (never fires here)
                atomicAdd(&emit[(size_t)we * N_LABELS + lab], 1.0f);
            }
            pre = lab;
        }
    }
    __syncthreads();

    if (use_part) {
        unsigned* p = part + (size_t)(blockIdx.x & (N_PART - 1)) * BINS;
        for (int k = threadIdx.x; k < BINS; k += BLOCK) {
            const unsigned c = hist[k];
            if (c) atomicAdd(p + k, c);
        }
    } else {
        for (int k = threadIdx.x; k < BINS; k += BLOCK) {
            const unsigned c = hist[k];
            if (c) atomicAdd(&out[k], (float)c);
        }
    }
}

__global__ __launch_bounds__(256)
void finalize_tc(const unsigned* __restrict__ part, float* __restrict__ out) {
    const int k = blockIdx.x * blockDim.x + threadIdx.x;
    if (k < BINS) {
        unsigned s = 0;
        #pragma unroll 8
        for (int p = 0; p < N_PART; ++p) s += part[(size_t)p * BINS + k];
        out[k] = (float)s;   // zero kernel already cleared; direct write of total
    }
}

extern "C" void kernel_launch(void* const* d_in, const int* in_sizes, int n_in,
                              void* d_out, int out_size, void* d_ws, size_t ws_size,
                              hipStream_t stream) {
    const int* words  = (const int*)d_in[0];
    const int* labels = (const int*)d_in[1];
    float* out = (float*)d_out;

    const int n      = in_sizes[0];     // BATCH * SEQ_LEN tokens
    const int nquads = n >> 2;

    const size_t part_bytes = (size_t)N_PART * BINS * sizeof(unsigned);
    const int use_part = (ws_size >= part_bytes) ? 1 : 0;

    const int out_quads  = out_size >> 2;
    const int part_quads = use_part ? (int)(part_bytes >> 4) : 0;

    zero_kernel<<<ZGRID, ZBLOCK, 0, stream>>>((uint4*)d_out, out_quads, out_size,
                                              (uint4*)d_ws, part_quads);
    count_kernel<<<GRID, BLOCK, 0, stream>>>(words, labels, out,
                                             (unsigned*)d_ws, nquads, use_part);
    if (use_part)
        finalize_tc<<<(BINS + 255) / 256, 256, 0, stream>>>(
            (const unsigned*)d_ws, out);
}

// Round 3
// 269.968 us; speedup vs baseline: 1.4160x; 1.4160x over previous
//
#include <hip/hip_runtime.h>
#include <hip/hip_bf16.h>

// HMM count-accumulation, atomic-free on the emit path.
// out = [trans_count 65*65=4225 | emit_count 500000*64=32M] floats.
//
// Device-scope atomics measured at ~30G/s on gfx950 (R1/R2: 165us for ~5.3M,
// occupancy-insensitive). Redesign: bucket tokens by emit partition (phase 1,
// one reservation atomic per (block,partition)), then each partition-owning
// block privately builds its 250KB slice in LDS chunks and writes every cell
// (phase 2) -- which also replaces the 128MB zero pass.

constexpr int N_WORDS  = 500000;
constexpr int N_LABELS = 64;
constexpr int SEQ_LEN  = 512;
constexpr int BINS     = (N_LABELS + 1) * (N_LABELS + 1);   // 4225
constexpr int N_CELLS  = N_WORDS * N_LABELS;                // 32,000,000
constexpr int P        = 512;     // emit partitions == phase-2 blocks
constexpr int CPP      = 62528;   // cells/partition, 64B-line aligned; 512*CPP >= N_CELLS
constexpr int CAP      = 16384;   // key slots per partition (mean ~6150, 2.7x margin)
constexpr int CHUNK    = 16384;   // LDS cells per phase-2 chunk (64KB)
constexpr int B1 = 1024, G1 = 512;
constexpr int B2 = 1024;

// ---------------- new path ----------------

__global__ __launch_bounds__(B1)
void phase1(const int* __restrict__ words, const int* __restrict__ labels,
            unsigned* __restrict__ cursors,        // [P] reservation cursors (zeroed)
            unsigned short* __restrict__ keys,     // [P][CAP] local cell ids
            unsigned* __restrict__ part_t,         // [G1][BINS] trans partials
            int nquads) {
    __shared__ unsigned trans[BINS];
    __shared__ unsigned cnt[P];
    __shared__ unsigned base[P];
    __shared__ unsigned pos[P];
    for (int k = threadIdx.x; k < BINS; k += B1) trans[k] = 0u;
    for (int k = threadIdx.x; k < P;    k += B1) { cnt[k] = 0u; pos[k] = 0u; }
    __syncthreads();

    const int stride = gridDim.x * blockDim.x;
    const int t0 = blockIdx.x * blockDim.x + threadIdx.x;

    // pass A: per-partition counts for this block
    for (int q = t0; q < nquads; q += stride) {
        const int4 w4 = reinterpret_cast<const int4*>(words)[q];
        const int4 l4 = reinterpret_cast<const int4*>(labels)[q];
        int wv[4] = {w4.x, w4.y, w4.z, w4.w};
        int lv[4] = {l4.x, l4.y, l4.z, l4.w};
        #pragma unroll
        for (int k = 0; k < 4; ++k) {
            if (wv[k] != 0) {
                const int w = (wv[k] >= N_WORDS) ? 1 : wv[k];
                const unsigned key = (unsigned)w * N_LABELS + (unsigned)lv[k];
                atomicAdd(&cnt[key / CPP], 1u);
            }
        }
    }
    __syncthreads();

    // reservation: ONE device atomic per (block, partition)
    for (int p = threadIdx.x; p < P; p += B1)
        base[p] = atomicAdd(&cursors[p], cnt[p]);
    __syncthreads();

    // pass B: place keys; trans histogram
    for (int q = t0; q < nquads; q += stride) {
        const int i = q << 2;
        const int4 w4 = reinterpret_cast<const int4*>(words)[q];
        const int4 l4 = reinterpret_cast<const int4*>(labels)[q];
        const int j0 = i & (SEQ_LEN - 1);
        int pre = (j0 == 0) ? N_LABELS : labels[i - 1];
        int wv[4] = {w4.x, w4.y, w4.z, w4.w};
        int lv[4] = {l4.x, l4.y, l4.z, l4.w};
        #pragma unroll
        for (int k = 0; k < 4; ++k) {
            const int lab = lv[k];
            if (wv[k] != 0) {
                atomicAdd(&trans[lab * (N_LABELS + 1) + pre], 1u);
                const int w = (wv[k] >= N_WORDS) ? 1 : wv[k];
                const unsigned key = (unsigned)w * N_LABELS + (unsigned)lab;
                const unsigned p   = key / CPP;
                const unsigned slot = base[p] + atomicAdd(&pos[p], 1u);
                if (slot < CAP)
                    keys[(size_t)p * CAP + slot] = (unsigned short)(key - p * CPP);
            }
            pre = lab;
        }
    }
    __syncthreads();

    // flush trans partials with plain coalesced stores (no atomics)
    unsigned* my = part_t + (size_t)blockIdx.x * BINS;
    for (int k = threadIdx.x; k < BINS; k += B1) my[k] = trans[k];
}

__global__ __launch_bounds__(B2)
void phase2(const unsigned* __restrict__ cursors,
            const unsigned short* __restrict__ keys,
            float* __restrict__ out) {
    extern __shared__ unsigned h[];                 // CHUNK u32 = 64KB
    const unsigned p = blockIdx.x;
    float* __restrict__ emit = out + BINS;
    const unsigned base_cell = p * (unsigned)CPP;
    const unsigned cells = min((unsigned)CPP, (unsigned)N_CELLS - base_cell);
    unsigned nk = cursors[p]; if (nk > CAP) nk = CAP;
    const unsigned short* kp = keys + (size_t)p * CAP;

    for (unsigned lo = 0; lo < cells; lo += CHUNK) {
        const unsigned hi = min(lo + (unsigned)CHUNK, cells);
        const unsigned n = hi - lo;
        for (unsigned j = threadIdx.x; j < n; j += B2) h[j] = 0u;
        __syncthreads();
        for (unsigned i = threadIdx.x; i < nk; i += B2) {
            const unsigned c = kp[i];
            if (c >= lo && c < hi) atomicAdd(&h[c - lo], 1u);
        }
        __syncthreads();
        for (unsigned j = threadIdx.x; j < n; j += B2)
            emit[base_cell + lo + j] = (float)h[j];
        __syncthreads();
    }
}

__global__ __launch_bounds__(256)
void finalize_new(const unsigned* __restrict__ part_t, float* __restrict__ out) {
    const int k = blockIdx.x;                       // bin, grid = BINS
    __shared__ unsigned red[256];
    unsigned s = 0;
    for (int pb = threadIdx.x; pb < G1; pb += 256)
        s += part_t[(size_t)pb * BINS + k];
    red[threadIdx.x] = s;
    __syncthreads();
    for (int off = 128; off > 0; off >>= 1) {
        if (threadIdx.x < (unsigned)off) red[threadIdx.x] += red[threadIdx.x + off];
        __syncthreads();
    }
    if (threadIdx.x == 0) out[k] = (float)red[0];
}

// ---------------- fallback path (R2 kernels, used only if ws too small) ----------------

__global__ __launch_bounds__(256)
void zero_kernel(uint4* __restrict__ out, int out_quads, int out_size) {
    const uint4 z = {0u, 0u, 0u, 0u};
    const int stride = gridDim.x * blockDim.x;
    for (int q = blockIdx.x * blockDim.x + threadIdx.x; q < out_quads; q += stride)
        out[q] = z;
    if (blockIdx.x == 0 && threadIdx.x < (out_size & 3))
        ((unsigned*)out)[(out_quads << 2) + threadIdx.x] = 0u;
}

__global__ __launch_bounds__(1024)
void count_fallback(const int* __restrict__ words, const int* __restrict__ labels,
                    float* __restrict__ out, int nquads) {
    __shared__ unsigned hist[BINS];
    for (int k = threadIdx.x; k < BINS; k += 1024) hist[k] = 0u;
    __syncthreads();
    float* __restrict__ emit = out + BINS;
    const int stride = gridDim.x * blockDim.x;
    for (int q = blockIdx.x * blockDim.x + threadIdx.x; q < nquads; q += stride) {
        const int i = q << 2;
        const int4 w4 = reinterpret_cast<const int4*>(words)[q];
        const int4 l4 = reinterpret_cast<const int4*>(labels)[q];
        const int j0 = i & (SEQ_LEN - 1);
        int pre = (j0 == 0) ? N_LABELS : labels[i - 1];
        int wv[4] = {w4.x, w4.y, w4.z, w4.w};
        int lv[4] = {l4.x, l4.y, l4.z, l4.w};
        #pragma unroll
        for (int k = 0; k < 4; ++k) {
            const int w = wv[k], lab = lv[k];
            if (w != 0) {
                atomicAdd(&hist[lab * (N_LABELS + 1) + pre], 1u);
                const int we = (w >= N_WORDS) ? 1 : w;
                atomicAdd(&emit[(size_t)we * N_LABELS + lab], 1.0f);
            }
            pre = lab;
        }
    }
    __syncthreads();
    for (int k = threadIdx.x; k < BINS; k += 1024) {
        const unsigned c = hist[k];
        if (c) atomicAdd(&out[k], (float)c);
    }
}

// ---------------- launch ----------------

extern "C" void kernel_launch(void* const* d_in, const int* in_sizes, int n_in,
                              void* d_out, int out_size, void* d_ws, size_t ws_size,
                              hipStream_t stream) {
    const int* words  = (const int*)d_in[0];
    const int* labels = (const int*)d_in[1];
    float* out = (float*)d_out;

    const int n      = in_sizes[0];
    const int nquads = n >> 2;

    // ws layout: [0,4KB) cursors | [4KB, 4KB+P*CAP*2) keys | trans partials
    const size_t cur_bytes  = 4096;
    const size_t key_bytes  = (size_t)P * CAP * sizeof(unsigned short);   // 16 MB
    const size_t part_bytes = (size_t)G1 * BINS * sizeof(unsigned);       // 8.65 MB
    const size_t need = cur_bytes + key_bytes + part_bytes;

    if (ws_size >= need) {
        unsigned* cursors      = (unsigned*)d_ws;
        unsigned short* keys   = (unsigned short*)((char*)d_ws + cur_bytes);
        unsigned* part_t       = (unsigned*)((char*)d_ws + cur_bytes + key_bytes);

        hipMemsetAsync(cursors, 0, P * sizeof(unsigned), stream);
        phase1<<<G1, B1, 0, stream>>>(words, labels, cursors, keys, part_t, nquads);
        phase2<<<P, B2, CHUNK * sizeof(unsigned), stream>>>(cursors, keys, out);
        finalize_new<<<BINS, 256, 0, stream>>>(part_t, out);
    } else {
        const int out_quads = out_size >> 2;
        zero_kernel<<<2048, 256, 0, stream>>>((uint4*)d_out, out_quads, out_size);
        count_fallback<<<512, 1024, 0, stream>>>(words, labels, out, nquads);
    }
}